// Round 2
// baseline (678.488 us; speedup 1.0000x reference)
//
#include <hip/hip_runtime.h>
#include <hip/hip_bf16.h>

typedef __attribute__((ext_vector_type(8))) short bf16x8;
typedef __attribute__((ext_vector_type(4))) float f32x4;

#define NEG_SLOPE 0.2f

__device__ __forceinline__ float bf2f(ushort u){ unsigned x=((unsigned)u)<<16; float f; __builtin_memcpy(&f,&x,4); return f; }
__device__ __forceinline__ ushort f2bf(float f){ __hip_bfloat16 h=__float2bfloat16(f); ushort u; __builtin_memcpy(&u,&h,2); return u; }
__device__ __forceinline__ float bflo(unsigned u){ return bf2f((ushort)(u&0xffffu)); }
__device__ __forceinline__ float bfhi(unsigned u){ return bf2f((ushort)(u>>16)); }
__device__ __forceinline__ float lrelu(float v){ return fmaxf(v,0.f) + NEG_SLOPE*fminf(v,0.f); }

struct U4 { unsigned v[4]; };

// ---------------- K0: build Wt[256][128] = [Wl|Wr]^T  (f32 -> bf16) ----------------
__global__ __launch_bounds__(256) void k_twt(const float* __restrict__ Wl, const float* __restrict__ Wr,
                                             ushort* __restrict__ Wt)
{
    int idx = blockIdx.x*256 + threadIdx.x;      // 0..32767
    if (idx >= 256*128) return;
    int c = idx >> 7, k = idx & 127;
    float v = (c < 128) ? Wl[k*128 + c] : Wr[k*128 + (c-128)];
    Wt[idx] = f2bf(v);
}

// ---------------- K1: MFMA GEMM  xl|xr = x @ [Wl|Wr] + [bl|br] ----------------
__global__ __launch_bounds__(256) void k_gemm(const float* __restrict__ x, const ushort* __restrict__ Wt,
                                              const float* __restrict__ bl, const float* __restrict__ br,
                                              ushort* __restrict__ xl, ushort* __restrict__ xr, int Nn)
{
    __shared__ ushort As[64*128];                 // 16KB bf16, XOR-swizzled 16B granules
    int tid = threadIdx.x;
    int wave = tid >> 6, lane = tid & 63;
    int l15 = lane & 15, l4 = lane >> 4;
    int row0 = blockIdx.x * 64;

    #pragma unroll
    for (int it = 0; it < 4; ++it) {
        int idx = tid + it*256;                   // granule id (8 cols each), 1024 total
        int r = idx >> 4;
        int g = idx & 15;
        float4 a = make_float4(0,0,0,0), b = make_float4(0,0,0,0);
        int g_row = row0 + r;
        if (g_row < Nn) {
            const float* p = x + (size_t)g_row*128 + g*8;
            a = *(const float4*)p;
            b = *(const float4*)(p + 4);
        }
        union { ushort us[8]; uint4 v; } P;
        P.us[0]=f2bf(a.x); P.us[1]=f2bf(a.y); P.us[2]=f2bf(a.z); P.us[3]=f2bf(a.w);
        P.us[4]=f2bf(b.x); P.us[5]=f2bf(b.y); P.us[6]=f2bf(b.z); P.us[7]=f2bf(b.w);
        int sw = (g*16) ^ ((r & 7) << 4);
        *(uint4*)((char*)As + r*256 + sw) = P.v;
    }
    __syncthreads();

    bf16x8 bfrag[4][4];
    #pragma unroll
    for (int nf = 0; nf < 4; ++nf) {
        int col = wave*64 + nf*16 + l15;
        const ushort* bp = Wt + (size_t)col*128;
        #pragma unroll
        for (int ks = 0; ks < 4; ++ks)
            bfrag[ks][nf] = *(const bf16x8*)(bp + ks*32 + l4*8);
    }
    f32x4 acc[4][4];
    #pragma unroll
    for (int i=0;i<4;++i)
        #pragma unroll
        for (int j=0;j<4;++j) acc[i][j] = (f32x4){0.f,0.f,0.f,0.f};

    #pragma unroll
    for (int ks = 0; ks < 4; ++ks) {
        bf16x8 afrag[4];
        #pragma unroll
        for (int mf = 0; mf < 4; ++mf) {
            int r = mf*16 + l15;
            int kbyte = ks*64 + l4*16;
            afrag[mf] = *(const bf16x8*)((char*)As + r*256 + (kbyte ^ ((r&7)<<4)));
        }
        #pragma unroll
        for (int mf = 0; mf < 4; ++mf)
            #pragma unroll
            for (int nf = 0; nf < 4; ++nf)
                acc[mf][nf] = __builtin_amdgcn_mfma_f32_16x16x32_bf16(afrag[mf], bfrag[ks][nf], acc[mf][nf], 0,0,0);
    }
    #pragma unroll
    for (int mf = 0; mf < 4; ++mf) {
        #pragma unroll
        for (int nf = 0; nf < 4; ++nf) {
            int col = wave*64 + nf*16 + l15;
            float bias = (col < 128) ? bl[col] : br[col-128];
            #pragma unroll
            for (int r = 0; r < 4; ++r) {
                int row = row0 + mf*16 + l4*4 + r;
                if (row < Nn) {
                    ushort o = f2bf(acc[mf][nf][r] + bias);
                    if (col < 128) xl[(size_t)row*128 + col] = o;
                    else           xr[(size_t)row*128 + (col-128)] = o;
                }
            }
        }
    }
}

// ---------------- K2: degree + attr_sum (atomics) ----------------
__global__ __launch_bounds__(256) void k_deg(const int* __restrict__ dst, const float* __restrict__ ea,
                                             int* __restrict__ deg_i, float* __restrict__ attr_sum, int E)
{
    int e = blockIdx.x*256 + threadIdx.x;
    if (e >= E) return;
    int d = dst[e];
    atomicAdd(&deg_i[d], 1);
    const float* a = ea + (size_t)e*8;
    float4 u0 = *(const float4*)a;
    float4 u1 = *(const float4*)(a + 4);
    float v[8] = {u0.x,u0.y,u0.z,u0.w,u1.x,u1.y,u1.z,u1.w};
    #pragma unroll
    for (int j=0;j<8;++j)
        if (v[j] != 0.f) atomicAdd(&attr_sum[(size_t)d*8 + j], v[j]);
}

// ---------------- scan kernels for CSR offsets ----------------
__global__ __launch_bounds__(256) void k_scan1(const int* __restrict__ deg_i, int* __restrict__ csr_off,
                                               int* __restrict__ partial)
{
    __shared__ int s[256];
    int i = blockIdx.x*256 + threadIdx.x;
    int v = deg_i[i];
    s[threadIdx.x] = v;
    __syncthreads();
    #pragma unroll
    for (int off=1; off<256; off<<=1){
        int t = (threadIdx.x >= off) ? s[threadIdx.x-off] : 0;
        __syncthreads();
        s[threadIdx.x] += t;
        __syncthreads();
    }
    csr_off[i] = s[threadIdx.x] - v;             // exclusive, block-local
    if (threadIdx.x == 255) partial[blockIdx.x] = s[255];
}

__global__ __launch_bounds__(256) void k_scan2(int* __restrict__ partial, int nb)
{
    __shared__ int s[256];
    int t = threadIdx.x;
    int v = (t < nb) ? partial[t] : 0;
    s[t] = v;
    __syncthreads();
    #pragma unroll
    for (int off=1; off<256; off<<=1){
        int u = (t >= off) ? s[t-off] : 0;
        __syncthreads();
        s[t] += u;
        __syncthreads();
    }
    if (t < nb) partial[t] = s[t] - v;           // exclusive block bases
}

__global__ __launch_bounds__(256) void k_scan3(int* __restrict__ csr_off, const int* __restrict__ partial)
{
    int i = blockIdx.x*256 + threadIdx.x;
    csr_off[i] += partial[blockIdx.x];
}

__global__ __launch_bounds__(256) void k_fill(const int* __restrict__ dst, int* __restrict__ cursor,
                                              const int* __restrict__ csr_off, int* __restrict__ csr_eid, int E)
{
    int e = blockIdx.x*256 + threadIdx.x;
    if (e >= E) return;
    int d = dst[e];
    int slot = atomicAdd(&cursor[d], 1);
    csr_eid[csr_off[d] + slot] = e;
}

// ---------------- K3: per-edge scores -> expd, denom ----------------
__global__ __launch_bounds__(256) void k_edge(const int* __restrict__ src, const int* __restrict__ dst,
    const float* __restrict__ ea, const ushort* __restrict__ xl, const ushort* __restrict__ xr,
    const float* __restrict__ We, const float* __restrict__ att,
    float* __restrict__ expd_e, float* __restrict__ denom, int E)
{
    int e = blockIdx.x*256 + threadIdx.x;
    if (e >= E) return;
    int s = src[e], d = dst[e];
    const float* a = ea + (size_t)e*8;
    float best = 0.f; int bt = 0;                 // edge_attr is one-hot: find nonzero type
    #pragma unroll
    for (int j=0;j<8;++j){
        float v = a[j];
        if (fabsf(v) > fabsf(best)) { best = v; bt = j; }
    }
    const float* emb = We + bt*128;
    const ushort* xls = xl + (size_t)s*128;
    const ushort* xrd = xr + (size_t)d*128;
    float ex[8];
    #pragma unroll
    for (int h=0; h<8; ++h){
        float dot = 0.f;
        #pragma unroll
        for (int q=0;q<2;++q){
            U4 A = *(const U4*)(xls + h*16 + q*8);
            U4 B = *(const U4*)(xrd + h*16 + q*8);
            const float* ep = emb + h*16 + q*8;
            const float* ap = att + h*16 + q*8;
            #pragma unroll
            for (int j=0;j<4;++j){
                float v0 = bflo(A.v[j]) + bflo(B.v[j]) + best*ep[2*j];
                float v1 = bfhi(A.v[j]) + bfhi(B.v[j]) + best*ep[2*j+1];
                dot += ap[2*j]*lrelu(v0) + ap[2*j+1]*lrelu(v1);
            }
        }
        ex[h] = __expf(dot);                      // no max-subtraction: |score| bounded ~10
    }
    #pragma unroll
    for (int h=0;h<8;++h){
        expd_e[(size_t)e*8 + h] = ex[h];
        atomicAdd(&denom[(size_t)d*8 + h], ex[h]);
    }
}

// ---------------- K4: self-loop scores (mean attr) ----------------
__global__ __launch_bounds__(256) void k_self(const int* __restrict__ deg_i, const float* __restrict__ attr_sum,
    const ushort* __restrict__ xl, const ushort* __restrict__ xr,
    const float* __restrict__ We, const float* __restrict__ att,
    float* __restrict__ expd_self, float* __restrict__ denom, int Nn)
{
    int n = blockIdx.x*256 + threadIdx.x;
    if (n >= Nn) return;
    float inv = 1.f / fmaxf((float)deg_i[n], 1.f);
    float eaw[8];
    #pragma unroll
    for (int t=0;t<8;++t) eaw[t] = attr_sum[(size_t)n*8 + t] * inv;
    const ushort* xln = xl + (size_t)n*128;
    const ushort* xrn = xr + (size_t)n*128;
    #pragma unroll
    for (int h=0;h<8;++h){
        float embv[16];
        #pragma unroll
        for (int i=0;i<16;++i) embv[i]=0.f;
        #pragma unroll
        for (int t=0;t<8;++t){
            float w = eaw[t];
            const float* wp = We + t*128 + h*16;
            #pragma unroll
            for (int c=0;c<16;++c) embv[c] += w*wp[c];
        }
        float dot = 0.f;
        #pragma unroll
        for (int q=0;q<2;++q){
            U4 A = *(const U4*)(xln + h*16 + q*8);
            U4 B = *(const U4*)(xrn + h*16 + q*8);
            const float* ap = att + h*16 + q*8;
            #pragma unroll
            for (int j=0;j<4;++j){
                float v0 = bflo(A.v[j]) + bflo(B.v[j]) + embv[q*8+2*j];
                float v1 = bfhi(A.v[j]) + bfhi(B.v[j]) + embv[q*8+2*j+1];
                dot += ap[2*j]*lrelu(v0) + ap[2*j+1]*lrelu(v1);
            }
        }
        float exd = __expf(dot);
        expd_self[(size_t)n*8 + h] = exd;
        denom[(size_t)n*8 + h] += exd;            // K3 finished: plain RMW is safe
    }
}

// ---------------- K5: wave-per-node aggregation + bias + LN + ELU ----------------
__global__ __launch_bounds__(256) void k_agg(const int* __restrict__ deg_i, const int* __restrict__ csr_off,
    const int* __restrict__ csr_eid, const int* __restrict__ src,
    const ushort* __restrict__ xl, const float* __restrict__ expd_e, const float* __restrict__ expd_self,
    const float* __restrict__ denom, const float* __restrict__ bias, const float* __restrict__ lnw,
    const float* __restrict__ lnb, float* __restrict__ out, int Nn)
{
    int wv = threadIdx.x >> 6, lane = threadIdx.x & 63;
    int n = blockIdx.x*4 + wv;
    if (n >= Nn) return;
    int h = lane >> 3;                            // channels c=2*lane,2*lane+1 -> head = lane/8
    float dinv = 1.f / denom[(size_t)n*8 + h];
    int beg = csr_off[n], cnt = deg_i[n];
    float a0=0.f, a1=0.f;
    for (int i=0;i<cnt;++i){
        int eid = csr_eid[beg+i];
        int sidx = src[eid];
        float al = expd_e[(size_t)eid*8 + h] * dinv;
        unsigned u = *(const unsigned*)(xl + (size_t)sidx*128 + lane*2);
        a0 += al*bflo(u); a1 += al*bfhi(u);
    }
    {   float al = expd_self[(size_t)n*8 + h] * dinv;
        unsigned u = *(const unsigned*)(xl + (size_t)n*128 + lane*2);
        a0 += al*bflo(u); a1 += al*bfhi(u);
    }
    {   float2 b = *(const float2*)(bias + lane*2);
        a0 += b.x; a1 += b.y;
    }
    float sum = a0 + a1;
    #pragma unroll
    for (int off=32; off>0; off>>=1) sum += __shfl_xor(sum, off);
    float mu = sum * (1.f/128.f);
    float d0 = a0-mu, d1 = a1-mu;
    float vs = d0*d0 + d1*d1;
    #pragma unroll
    for (int off=32; off>0; off>>=1) vs += __shfl_xor(vs, off);
    float rs = rsqrtf(vs*(1.f/128.f) + 1e-5f);
    float2 w = *(const float2*)(lnw + lane*2);
    float2 bb = *(const float2*)(lnb + lane*2);
    float y0 = d0*rs*w.x + bb.x;
    float y1 = d1*rs*w.y + bb.y;
    y0 = (y0 > 0.f) ? y0 : (__expf(y0) - 1.f);
    y1 = (y1 > 0.f) ? y1 : (__expf(y1) - 1.f);
    *(float2*)(out + (size_t)n*128 + lane*2) = make_float2(y0, y1);
}

extern "C" void kernel_launch(void* const* d_in, const int* in_sizes, int n_in,
                              void* d_out, int out_size, void* d_ws, size_t ws_size,
                              hipStream_t stream)
{
    const float* x   = (const float*)d_in[0];
    const int*   src = (const int*)  d_in[1];
    const int*   dst = (const int*)  d_in[2];
    const float* ea  = (const float*)d_in[3];
    const float* Wl  = (const float*)d_in[4];
    const float* bl  = (const float*)d_in[5];
    const float* Wr  = (const float*)d_in[6];
    const float* br  = (const float*)d_in[7];
    const float* We  = (const float*)d_in[8];
    const float* att = (const float*)d_in[9];
    const float* bias= (const float*)d_in[10];
    const float* lnw = (const float*)d_in[11];
    const float* lnb = (const float*)d_in[12];
    float* out = (float*)d_out;

    const int N  = in_sizes[0] / 128;
    const int E  = in_sizes[1];
    const int NP = ((N + 255)/256)*256;
    const int MB = (N + 63)/64;
    const int SB = NP/256;

    char* base = (char*)d_ws;
    size_t o = 0;
    auto alloc = [&](size_t b){ size_t r = o; o += (b + 255) & ~(size_t)255; return r; };
    ushort* Wt       = (ushort*)(base + alloc(256*128*2));
    ushort* xl       = (ushort*)(base + alloc((size_t)MB*64*128*2));
    ushort* xr       = (ushort*)(base + alloc((size_t)MB*64*128*2));
    size_t zoff = o;
    int*    deg_i    = (int*)   (base + alloc((size_t)NP*4));
    int*    cursor   = (int*)   (base + alloc((size_t)NP*4));
    float*  attr_sum = (float*) (base + alloc((size_t)NP*8*4));
    float*  denom    = (float*) (base + alloc((size_t)NP*8*4));
    size_t zbytes = o - zoff;
    int*    csr_off  = (int*)   (base + alloc((size_t)NP*4));
    int*    partial  = (int*)   (base + alloc(256*4));
    int*    csr_eid  = (int*)   (base + alloc((size_t)E*4));
    float*  expd_e   = (float*) (base + alloc((size_t)E*8*4));
    float*  expd_self= (float*) (base + alloc((size_t)NP*8*4));
    (void)ws_size; (void)n_in; (void)out_size;

    hipMemsetAsync(base + zoff, 0, zbytes, stream);
    k_twt  <<<128, 256, 0, stream>>>(Wl, Wr, Wt);
    k_gemm <<<MB,  256, 0, stream>>>(x, Wt, bl, br, xl, xr, N);
    k_deg  <<<(E+255)/256, 256, 0, stream>>>(dst, ea, deg_i, attr_sum, E);
    k_scan1<<<SB,  256, 0, stream>>>(deg_i, csr_off, partial);
    k_scan2<<<1,   256, 0, stream>>>(partial, SB);
    k_scan3<<<SB,  256, 0, stream>>>(csr_off, partial);
    k_fill <<<(E+255)/256, 256, 0, stream>>>(dst, cursor, csr_off, csr_eid, E);
    k_edge <<<(E+255)/256, 256, 0, stream>>>(src, dst, ea, xl, xr, We, att, expd_e, denom, E);
    k_self <<<SB,  256, 0, stream>>>(deg_i, attr_sum, xl, xr, We, att, expd_self, denom, N);
    k_agg  <<<(N+3)/4, 256, 0, stream>>>(deg_i, csr_off, csr_eid, src, xl, expd_e, expd_self, denom,
                                         bias, lnw, lnb, out, N);
}

// Round 3
// 270.546 us; speedup vs baseline: 2.5079x; 2.5079x over previous
//
#include <hip/hip_runtime.h>
#include <hip/hip_bf16.h>

typedef __attribute__((ext_vector_type(8))) short bf16x8;
typedef __attribute__((ext_vector_type(4))) float f32x4;

#define NEG_SLOPE 0.2f

__device__ __forceinline__ float bf2f(ushort u){ unsigned x=((unsigned)u)<<16; float f; __builtin_memcpy(&f,&x,4); return f; }
__device__ __forceinline__ ushort f2bf(float f){ __hip_bfloat16 h=__float2bfloat16(f); ushort u; __builtin_memcpy(&u,&h,2); return u; }
__device__ __forceinline__ float bflo(unsigned u){ return bf2f((ushort)(u&0xffffu)); }
__device__ __forceinline__ float bfhi(unsigned u){ return bf2f((ushort)(u>>16)); }
__device__ __forceinline__ float lrelu(float v){ return fmaxf(v,0.f) + NEG_SLOPE*fminf(v,0.f); }

struct U4 { unsigned v[4]; };

// ---------------- K0: build Wt[256][128] = [Wl|Wr]^T  (f32 -> bf16) ----------------
__global__ __launch_bounds__(256) void k_twt(const float* __restrict__ Wl, const float* __restrict__ Wr,
                                             ushort* __restrict__ Wt)
{
    int idx = blockIdx.x*256 + threadIdx.x;      // 0..32767
    if (idx >= 256*128) return;
    int c = idx >> 7, k = idx & 127;
    float v = (c < 128) ? Wl[k*128 + c] : Wr[k*128 + (c-128)];
    Wt[idx] = f2bf(v);
}

// ---------------- K1: MFMA GEMM  xl|xr = x @ [Wl|Wr] + [bl|br] ----------------
__global__ __launch_bounds__(256) void k_gemm(const float* __restrict__ x, const ushort* __restrict__ Wt,
                                              const float* __restrict__ bl, const float* __restrict__ br,
                                              ushort* __restrict__ xl, ushort* __restrict__ xr, int Nn)
{
    __shared__ ushort As[64*128];                 // 16KB bf16, XOR-swizzled 16B granules
    int tid = threadIdx.x;
    int wave = tid >> 6, lane = tid & 63;
    int l15 = lane & 15, l4 = lane >> 4;
    int row0 = blockIdx.x * 64;

    #pragma unroll
    for (int it = 0; it < 4; ++it) {
        int idx = tid + it*256;                   // granule id (8 cols each), 1024 total
        int r = idx >> 4;
        int g = idx & 15;
        float4 a = make_float4(0,0,0,0), b = make_float4(0,0,0,0);
        int g_row = row0 + r;
        if (g_row < Nn) {
            const float* p = x + (size_t)g_row*128 + g*8;
            a = *(const float4*)p;
            b = *(const float4*)(p + 4);
        }
        union { ushort us[8]; uint4 v; } P;
        P.us[0]=f2bf(a.x); P.us[1]=f2bf(a.y); P.us[2]=f2bf(a.z); P.us[3]=f2bf(a.w);
        P.us[4]=f2bf(b.x); P.us[5]=f2bf(b.y); P.us[6]=f2bf(b.z); P.us[7]=f2bf(b.w);
        int sw = (g*16) ^ ((r & 7) << 4);
        *(uint4*)((char*)As + r*256 + sw) = P.v;
    }
    __syncthreads();

    bf16x8 bfrag[4][4];
    #pragma unroll
    for (int nf = 0; nf < 4; ++nf) {
        int col = wave*64 + nf*16 + l15;
        const ushort* bp = Wt + (size_t)col*128;
        #pragma unroll
        for (int ks = 0; ks < 4; ++ks)
            bfrag[ks][nf] = *(const bf16x8*)(bp + ks*32 + l4*8);
    }
    f32x4 acc[4][4];
    #pragma unroll
    for (int i=0;i<4;++i)
        #pragma unroll
        for (int j=0;j<4;++j) acc[i][j] = (f32x4){0.f,0.f,0.f,0.f};

    #pragma unroll
    for (int ks = 0; ks < 4; ++ks) {
        bf16x8 afrag[4];
        #pragma unroll
        for (int mf = 0; mf < 4; ++mf) {
            int r = mf*16 + l15;
            int kbyte = ks*64 + l4*16;
            afrag[mf] = *(const bf16x8*)((char*)As + r*256 + (kbyte ^ ((r&7)<<4)));
        }
        #pragma unroll
        for (int mf = 0; mf < 4; ++mf)
            #pragma unroll
            for (int nf = 0; nf < 4; ++nf)
                acc[mf][nf] = __builtin_amdgcn_mfma_f32_16x16x32_bf16(afrag[mf], bfrag[ks][nf], acc[mf][nf], 0,0,0);
    }
    #pragma unroll
    for (int mf = 0; mf < 4; ++mf) {
        #pragma unroll
        for (int nf = 0; nf < 4; ++nf) {
            int col = wave*64 + nf*16 + l15;
            float bias = (col < 128) ? bl[col] : br[col-128];
            #pragma unroll
            for (int r = 0; r < 4; ++r) {
                int row = row0 + mf*16 + l4*4 + r;
                if (row < Nn) {
                    ushort o = f2bf(acc[mf][nf][r] + bias);
                    if (col < 128) xl[(size_t)row*128 + col] = o;
                    else           xr[(size_t)row*128 + (col-128)] = o;
                }
            }
        }
    }
}

// ---------------- K2: degree + attr_sum + edge type (atomics) ----------------
__global__ __launch_bounds__(256) void k_deg(const int* __restrict__ dst, const float* __restrict__ ea,
                                             int* __restrict__ deg_i, float* __restrict__ attr_sum,
                                             unsigned char* __restrict__ etype_e, float* __restrict__ scale_e, int E)
{
    int e = blockIdx.x*256 + threadIdx.x;
    if (e >= E) return;
    int d = dst[e];
    atomicAdd(&deg_i[d], 1);
    const float* a = ea + (size_t)e*8;
    float4 u0 = *(const float4*)a;
    float4 u1 = *(const float4*)(a + 4);
    float v[8] = {u0.x,u0.y,u0.z,u0.w,u1.x,u1.y,u1.z,u1.w};
    float best = 0.f; int bt = 0;                 // one-hot: find the nonzero component
    #pragma unroll
    for (int j=0;j<8;++j)
        if (fabsf(v[j]) > fabsf(best)) { best = v[j]; bt = j; }
    etype_e[e] = (unsigned char)bt;
    scale_e[e] = best;
    if (best != 0.f) atomicAdd(&attr_sum[(size_t)d*8 + bt], best);
}

// ---------------- scan kernels for CSR offsets ----------------
__global__ __launch_bounds__(256) void k_scan1(const int* __restrict__ deg_i, int* __restrict__ csr_off,
                                               int* __restrict__ partial)
{
    __shared__ int s[256];
    int i = blockIdx.x*256 + threadIdx.x;
    int v = deg_i[i];
    s[threadIdx.x] = v;
    __syncthreads();
    #pragma unroll
    for (int off=1; off<256; off<<=1){
        int t = (threadIdx.x >= off) ? s[threadIdx.x-off] : 0;
        __syncthreads();
        s[threadIdx.x] += t;
        __syncthreads();
    }
    csr_off[i] = s[threadIdx.x] - v;             // exclusive, block-local
    if (threadIdx.x == 255) partial[blockIdx.x] = s[255];
}

__global__ __launch_bounds__(256) void k_scan2(int* __restrict__ partial, int nb)
{
    __shared__ int s[256];
    int t = threadIdx.x;
    int v = (t < nb) ? partial[t] : 0;
    s[t] = v;
    __syncthreads();
    #pragma unroll
    for (int off=1; off<256; off<<=1){
        int u = (t >= off) ? s[t-off] : 0;
        __syncthreads();
        s[t] += u;
        __syncthreads();
    }
    if (t < nb) partial[t] = s[t] - v;           // exclusive block bases
}

__global__ __launch_bounds__(256) void k_scan3(int* __restrict__ csr_off, const int* __restrict__ partial)
{
    int i = blockIdx.x*256 + threadIdx.x;
    csr_off[i] += partial[blockIdx.x];
}

// ---------------- K3: per-edge scores, 4 edges/wave, CSR-ordered output ----------------
// 16 lanes per edge, 16B (8 bf16 channels) per lane -> fully coalesced 256B row reads.
// Fuses CSR fill: lane 0 allocates the slot; expd and src written in CSR order.
__global__ __launch_bounds__(256) void k_edge(const int* __restrict__ src, const int* __restrict__ dst,
    const unsigned char* __restrict__ etype_e, const float* __restrict__ scale_e,
    const ushort* __restrict__ xl, const ushort* __restrict__ xr,
    const float* __restrict__ We, const float* __restrict__ att,
    int* __restrict__ cursor, const int* __restrict__ csr_off,
    float* __restrict__ expd_csr, int* __restrict__ csr_src, int E)
{
    int wid = (blockIdx.x*256 + threadIdx.x) >> 6;
    int lane = threadIdx.x & 63;
    int l = lane & 15;                            // lane within edge
    int e = wid*4 + (lane >> 4);
    if (e >= E) return;
    int s = src[e], d = dst[e];
    int et = etype_e[e];
    float sc = scale_e[e];
    bf16x8 na = *(const bf16x8*)(xl + (size_t)s*128 + l*8);
    bf16x8 nb = *(const bf16x8*)(xr + (size_t)d*128 + l*8);
    const float* ep = We + et*128 + l*8;
    const float* ap = att + l*8;
    float p = 0.f;
    #pragma unroll
    for (int j=0;j<8;++j){
        float v = bf2f((ushort)na[j]) + bf2f((ushort)nb[j]) + sc*ep[j];
        p += ap[j]*lrelu(v);
    }
    p += __shfl_xor(p, 1);                        // head sum (2 lanes/head)
    int sb = 0;
    if (l == 0) sb = csr_off[d] + atomicAdd(&cursor[d], 1);
    sb = __shfl(sb, lane & 48);                   // broadcast within 16-lane group
    if ((l & 1) == 0) expd_csr[(size_t)sb*8 + (l>>1)] = __expf(p);
    if (l == 1) csr_src[sb] = s;
}

// ---------------- K4: self-loop scores (mean attr) ----------------
__global__ __launch_bounds__(256) void k_self(const int* __restrict__ deg_i, const float* __restrict__ attr_sum,
    const ushort* __restrict__ xl, const ushort* __restrict__ xr,
    const float* __restrict__ We, const float* __restrict__ att,
    float* __restrict__ expd_self, int Nn)
{
    int n = blockIdx.x*256 + threadIdx.x;
    if (n >= Nn) return;
    float inv = 1.f / fmaxf((float)deg_i[n], 1.f);
    float eaw[8];
    #pragma unroll
    for (int t=0;t<8;++t) eaw[t] = attr_sum[(size_t)n*8 + t] * inv;
    const ushort* xln = xl + (size_t)n*128;
    const ushort* xrn = xr + (size_t)n*128;
    #pragma unroll
    for (int h=0;h<8;++h){
        float embv[16];
        #pragma unroll
        for (int i=0;i<16;++i) embv[i]=0.f;
        #pragma unroll
        for (int t=0;t<8;++t){
            float w = eaw[t];
            const float* wp = We + t*128 + h*16;
            #pragma unroll
            for (int c=0;c<16;++c) embv[c] += w*wp[c];
        }
        float dot = 0.f;
        #pragma unroll
        for (int q=0;q<2;++q){
            U4 A = *(const U4*)(xln + h*16 + q*8);
            U4 B = *(const U4*)(xrn + h*16 + q*8);
            const float* ap = att + h*16 + q*8;
            #pragma unroll
            for (int j=0;j<4;++j){
                float v0 = bflo(A.v[j]) + bflo(B.v[j]) + embv[q*8+2*j];
                float v1 = bfhi(A.v[j]) + bfhi(B.v[j]) + embv[q*8+2*j+1];
                dot += ap[2*j]*lrelu(v0) + ap[2*j+1]*lrelu(v1);
            }
        }
        expd_self[(size_t)n*8 + h] = __expf(dot);
    }
}

// ---------------- K5: wave-per-node aggregation (single pass, no atomics) + LN + ELU ----------------
__global__ __launch_bounds__(256) void k_agg(const int* __restrict__ deg_i, const int* __restrict__ csr_off,
    const int* __restrict__ csr_src,
    const ushort* __restrict__ xl, const float* __restrict__ expd_csr, const float* __restrict__ expd_self,
    const float* __restrict__ bias, const float* __restrict__ lnw,
    const float* __restrict__ lnb, float* __restrict__ out, int Nn)
{
    int wv = threadIdx.x >> 6, lane = threadIdx.x & 63;
    int n = blockIdx.x*4 + wv;
    if (n >= Nn) return;
    int h = lane >> 3;                            // channels c=2*lane,2*lane+1 -> head = lane/8
    int beg = csr_off[n], cnt = deg_i[n];
    float a0=0.f, a1=0.f, den=0.f;
    #pragma unroll 2
    for (int i=0;i<cnt;++i){
        int sidx = csr_src[beg+i];
        float ex = expd_csr[(size_t)(beg+i)*8 + h];
        unsigned u = *(const unsigned*)(xl + (size_t)sidx*128 + lane*2);
        a0 += ex*bflo(u); a1 += ex*bfhi(u); den += ex;
    }
    {   float ex = expd_self[(size_t)n*8 + h];
        unsigned u = *(const unsigned*)(xl + (size_t)n*128 + lane*2);
        a0 += ex*bflo(u); a1 += ex*bfhi(u); den += ex;
    }
    float dinv = 1.f/den;
    {   float2 b = *(const float2*)(bias + lane*2);
        a0 = a0*dinv + b.x; a1 = a1*dinv + b.y;
    }
    float sum = a0 + a1;
    #pragma unroll
    for (int off=32; off>0; off>>=1) sum += __shfl_xor(sum, off);
    float mu = sum * (1.f/128.f);
    float d0 = a0-mu, d1 = a1-mu;
    float vs = d0*d0 + d1*d1;
    #pragma unroll
    for (int off=32; off>0; off>>=1) vs += __shfl_xor(vs, off);
    float rs = rsqrtf(vs*(1.f/128.f) + 1e-5f);
    float2 w = *(const float2*)(lnw + lane*2);
    float2 bb = *(const float2*)(lnb + lane*2);
    float y0 = d0*rs*w.x + bb.x;
    float y1 = d1*rs*w.y + bb.y;
    y0 = (y0 > 0.f) ? y0 : (__expf(y0) - 1.f);
    y1 = (y1 > 0.f) ? y1 : (__expf(y1) - 1.f);
    *(float2*)(out + (size_t)n*128 + lane*2) = make_float2(y0, y1);
}

extern "C" void kernel_launch(void* const* d_in, const int* in_sizes, int n_in,
                              void* d_out, int out_size, void* d_ws, size_t ws_size,
                              hipStream_t stream)
{
    const float* x   = (const float*)d_in[0];
    const int*   src = (const int*)  d_in[1];
    const int*   dst = (const int*)  d_in[2];
    const float* ea  = (const float*)d_in[3];
    const float* Wl  = (const float*)d_in[4];
    const float* bl  = (const float*)d_in[5];
    const float* Wr  = (const float*)d_in[6];
    const float* br  = (const float*)d_in[7];
    const float* We  = (const float*)d_in[8];
    const float* att = (const float*)d_in[9];
    const float* bias= (const float*)d_in[10];
    const float* lnw = (const float*)d_in[11];
    const float* lnb = (const float*)d_in[12];
    float* out = (float*)d_out;

    const int N  = in_sizes[0] / 128;
    const int E  = in_sizes[1];
    const int NP = ((N + 255)/256)*256;
    const int MB = (N + 63)/64;
    const int SB = NP/256;

    char* base = (char*)d_ws;
    size_t o = 0;
    auto alloc = [&](size_t b){ size_t r = o; o += (b + 255) & ~(size_t)255; return r; };
    ushort* Wt       = (ushort*)(base + alloc(256*128*2));
    ushort* xl       = (ushort*)(base + alloc((size_t)MB*64*128*2));
    ushort* xr       = (ushort*)(base + alloc((size_t)MB*64*128*2));
    size_t zoff = o;
    int*    deg_i    = (int*)   (base + alloc((size_t)NP*4));
    int*    cursor   = (int*)   (base + alloc((size_t)NP*4));
    float*  attr_sum = (float*) (base + alloc((size_t)NP*8*4));
    size_t zbytes = o - zoff;
    int*    csr_off  = (int*)   (base + alloc((size_t)NP*4));
    int*    partial  = (int*)   (base + alloc(256*4));
    int*    csr_src  = (int*)   (base + alloc((size_t)E*4));
    float*  expd_csr = (float*) (base + alloc((size_t)E*8*4));
    float*  expd_self= (float*) (base + alloc((size_t)NP*8*4));
    unsigned char* etype_e = (unsigned char*)(base + alloc((size_t)E));
    float*  scale_e  = (float*) (base + alloc((size_t)E*4));
    (void)ws_size; (void)n_in; (void)out_size;

    hipMemsetAsync(base + zoff, 0, zbytes, stream);
    k_twt  <<<128, 256, 0, stream>>>(Wl, Wr, Wt);
    k_gemm <<<MB,  256, 0, stream>>>(x, Wt, bl, br, xl, xr, N);
    k_deg  <<<(E+255)/256, 256, 0, stream>>>(dst, ea, deg_i, attr_sum, etype_e, scale_e, E);
    k_scan1<<<SB,  256, 0, stream>>>(deg_i, csr_off, partial);
    k_scan2<<<1,   256, 0, stream>>>(partial, SB);
    k_scan3<<<SB,  256, 0, stream>>>(csr_off, partial);
    k_edge <<<(E*16+255)/256, 256, 0, stream>>>(src, dst, etype_e, scale_e, xl, xr, We, att,
                                                cursor, csr_off, expd_csr, csr_src, E);
    k_self <<<SB,  256, 0, stream>>>(deg_i, attr_sum, xl, xr, We, att, expd_self, N);
    k_agg  <<<(N+3)/4, 256, 0, stream>>>(deg_i, csr_off, csr_src, xl, expd_csr, expd_self,
                                         bias, lnw, lnb, out, N);
}